// Round 2
// baseline (35312.607 us; speedup 1.0000x reference)
//
#include <hip/hip_runtime.h>

typedef _Float16 half_t;
typedef _Float16 f16x2 __attribute__((ext_vector_type(2)));
typedef _Float16 f16x8 __attribute__((ext_vector_type(8)));
typedef float f32x4 __attribute__((ext_vector_type(4)));

#define B_SZ 64
#define T_SZ 2048
#define F_SZ 256
#define H_SZ 512
#define O_SZ 128

#if defined(__has_builtin)
#if __has_builtin(__builtin_amdgcn_fdot2)
#define HAS_FDOT2 1
#endif
#endif
#ifndef HAS_FDOT2
#define HAS_FDOT2 0
#endif

static __device__ __forceinline__ float fdot2(unsigned int w, unsigned int h, float acc) {
#if HAS_FDOT2
    return __builtin_amdgcn_fdot2(__builtin_bit_cast(f16x2, w), __builtin_bit_cast(f16x2, h), acc, false);
#else
    f16x2 wv = __builtin_bit_cast(f16x2, w);
    f16x2 hv = __builtin_bit_cast(f16x2, h);
    return acc + (float)wv[0] * (float)hv[0] + (float)wv[1] * (float)hv[1];
#endif
}

// ---------------- prep kernels ----------------

__global__ void cvt_f32_f16(const float* __restrict__ src, half_t* __restrict__ dst, int n) {
    int i = blockIdx.x * 256 + threadIdx.x;
    if (i < n) dst[i] = (half_t)src[i];
}

__global__ void zero_flags(unsigned int* __restrict__ p, int n) {
    int i = blockIdx.x * 256 + threadIdx.x;
    if (i < n) p[i] = 0u;
}

// ---------------- input-projection GEMM (MFMA f16) ----------------
// C[m][n] = sum_k A[m][k] * Bw[n][k] + bias1[n] + bias2[n], N = 512 fixed.
template<bool A_F32, int K>
__global__ __launch_bounds__(256) void gemm_xp(const void* __restrict__ Aptr,
                                               const half_t* __restrict__ Bw,
                                               const float* __restrict__ bias1,
                                               const float* __restrict__ bias2,
                                               half_t* __restrict__ Cout)
{
    const int nt   = blockIdx.x & 7;     // N/64 = 8
    const int mt   = blockIdx.x >> 3;
    const int wave = threadIdx.x >> 6;
    const int lane = threadIdx.x & 63;
    const int mrow = mt * 64 + wave * 16 + (lane & 15);
    const int koff = (lane >> 4) * 8;

    f32x4 acc[4];
#pragma unroll
    for (int i = 0; i < 4; i++) acc[i] = (f32x4){0.f, 0.f, 0.f, 0.f};

#pragma unroll 2
    for (int k0 = 0; k0 < K; k0 += 32) {
        f16x8 a;
        if (A_F32) {
            const float* ap = (const float*)Aptr + (size_t)mrow * K + (k0 + koff);
            float4 v0 = ((const float4*)ap)[0];
            float4 v1 = ((const float4*)ap)[1];
            a[0] = (half_t)v0.x; a[1] = (half_t)v0.y; a[2] = (half_t)v0.z; a[3] = (half_t)v0.w;
            a[4] = (half_t)v1.x; a[5] = (half_t)v1.y; a[6] = (half_t)v1.z; a[7] = (half_t)v1.w;
        } else {
            const half_t* ap = (const half_t*)Aptr + (size_t)mrow * K + (k0 + koff);
            a = *(const f16x8*)ap;
        }
#pragma unroll
        for (int cb = 0; cb < 4; cb++) {
            const int col = nt * 64 + cb * 16 + (lane & 15);
            f16x8 bfrag = *(const f16x8*)(Bw + (size_t)col * K + (k0 + koff));
            acc[cb] = __builtin_amdgcn_mfma_f32_16x16x32_f16(a, bfrag, acc[cb], 0, 0, 0);
        }
    }
    const int rbase = mt * 64 + wave * 16 + (lane >> 4) * 4;
#pragma unroll
    for (int cb = 0; cb < 4; cb++) {
        const int col = nt * 64 + cb * 16 + (lane & 15);
        const float bsum = bias1[col] + bias2[col];
#pragma unroll
        for (int r = 0; r < 4; r++) {
            Cout[(size_t)(rbase + r) * H_SZ + col] = (half_t)(acc[cb][r] + bsum);
        }
    }
}

// ---------------- recurrence kernel: 4-WG output-split, W in registers ----------------
// Grid = 256 WGs of 512 threads. Group g (= batch row) has 4 members m.
// Member m owns output rows [128m, 128m+128). Thread (o=tid&127, s=tid>>7):
// partial dot of output row j=128m+o over k in [128s, 128s+128), W held in
// 64 VGPRs (half2). Per step: reg-dot -> LDS reduce -> tanh -> publish own
// 128-half chunk (agent-scope atomics, parity double-buffered) -> flag
// (release) -> spin on 3 remote flags -> install remote chunks into LDS.
// Flags monotonic (t+1), zeroed each launch by zero_flags.
__global__ __launch_bounds__(512, 2)
void rnn_rec4(half_t* xpres,                    // [B,T,512] xp in (res out in place if store_res)
              const int store_res,
              const float* __restrict__ Whh,    // [512,512] f32
              const float* __restrict__ h0,     // [512]
              float* hT,                        // [B,512] or nullptr
              half_t* __restrict__ xch,         // [64][2][4][128] half
              unsigned int* __restrict__ flags) // [64][4][16] uint
{
    __shared__ __align__(16) half_t h_sh[H_SZ];
    __shared__ float part[4 * 128];

    const int blk = blockIdx.x;
    // same-XCD grouping heuristic under round-robin blk%8 -> XCD (correctness-neutral)
    const int xcd = blk & 7;
    const int ii  = blk >> 3;
    const int g   = (ii & 7) * 8 + xcd;   // group = batch row, 0..63
    const int m   = ii >> 3;              // member 0..3
    const int tid = threadIdx.x;
    const int o   = tid & 127;
    const int s   = tid >> 7;
    const int j   = m * 128 + o;          // my output row

    // ---- one-time: W slice into registers (64 half2 = 64 VGPRs) ----
    unsigned int wreg[64];
    {
        const float* wrow = Whh + (size_t)j * H_SZ + s * 128;
#pragma unroll
        for (int kk = 0; kk < 64; kk++) {
            f16x2 h2;
            h2[0] = (half_t)wrow[2 * kk];
            h2[1] = (half_t)wrow[2 * kk + 1];
            wreg[kk] = __builtin_bit_cast(unsigned int, h2);
        }
    }
    h_sh[tid] = (half_t)h0[tid];
    __syncthreads();

    const size_t xbase = (size_t)g * T_SZ * H_SZ + m * 128;
    unsigned int* myflag = flags + ((size_t)g * 4 + m) * 16;

    // prefetch xp for t=0
    float xpv_next = (tid < 128) ? (float)xpres[xbase + o] : 0.f;

    for (int t = 0; t < T_SZ; t++) {
        const float xpv = xpv_next;
        if (tid < 128 && t + 1 < T_SZ)
            xpv_next = (float)xpres[xbase + (size_t)(t + 1) * H_SZ + o];

        // ---- dot: W (regs) x h (LDS broadcast) over my k-slice ----
        const uint4* hs4 = (const uint4*)h_sh + s * 16;   // wave-uniform address
        float acc = 0.f;
#pragma unroll
        for (int i2 = 0; i2 < 16; i2++) {
            uint4 h4 = hs4[i2];
            acc = fdot2(wreg[4 * i2 + 0], h4.x, acc);
            acc = fdot2(wreg[4 * i2 + 1], h4.y, acc);
            acc = fdot2(wreg[4 * i2 + 2], h4.z, acc);
            acc = fdot2(wreg[4 * i2 + 3], h4.w, acc);
        }
        part[s * 128 + o] = acc;
        __syncthreads();                                  // A: partials + h reads done

        if (s == 0) {  // tid < 128: reduce + tanh + own chunk into LDS
            float y = part[o] + part[128 + o] + part[256 + o] + part[384 + o] + xpv;
            float hv = tanhf(y);
            h_sh[j] = (half_t)hv;
            if (store_res) xpres[xbase + (size_t)t * H_SZ + o] = (half_t)hv;
            if (hT != nullptr && t == T_SZ - 1) hT[(size_t)g * H_SZ + j] = hv;
        }
        __syncthreads();                                  // X: own chunk ready in LDS

        const int par = (t + 1) & 1;
        // publish own chunk: wave 0 lanes 0..31, 8B agent-scope stores
        if (tid < 32) {
            const unsigned long long* src = (const unsigned long long*)(h_sh + m * 128);
            unsigned long long v = src[tid];
            unsigned long long* dst =
                (unsigned long long*)(xch + (((size_t)g * 2 + par) * 4 + m) * 128);
            __hip_atomic_store(&dst[tid], v, __ATOMIC_RELAXED, __HIP_MEMORY_SCOPE_AGENT);
        }
        if (tid == 0) {  // same wave: release orders the 32 chunk stores before the flag
            __hip_atomic_store(myflag, (unsigned int)(t + 1), __ATOMIC_RELEASE,
                               __HIP_MEMORY_SCOPE_AGENT);
        }
        // spin on 3 remote flags: wave 1 lanes 0..2
        if (tid >= 64 && tid < 67) {
            int rm = tid - 64;
            rm += (rm >= m);
            const unsigned int* rf = flags + ((size_t)g * 4 + rm) * 16;
            while (__hip_atomic_load(rf, __ATOMIC_ACQUIRE, __HIP_MEMORY_SCOPE_AGENT) <
                   (unsigned int)(t + 1)) {
                __builtin_amdgcn_s_sleep(1);
            }
        }
        __syncthreads();                                  // Y: all remote chunks published

        // install remote chunks: 3 chunks x 32 x 8B
        if (tid < 96) {
            int rm = tid >> 5;
            rm += (rm >= m);
            const int e = tid & 31;
            const unsigned long long* src =
                (const unsigned long long*)(xch + (((size_t)g * 2 + par) * 4 + rm) * 128);
            unsigned long long v =
                __hip_atomic_load(&src[e], __ATOMIC_RELAXED, __HIP_MEMORY_SCOPE_AGENT);
            ((unsigned long long*)(h_sh + rm * 128))[e] = v;
        }
        __syncthreads();                                  // Z: h for t+1 complete
    }
}

// ---------------- head: out[b][o] = dot(hT[b], W_fc[o]) + b_fc[o] ----------------
__global__ __launch_bounds__(128) void head_fc(const float* __restrict__ hT,
                                               const float* __restrict__ Wfc,
                                               const float* __restrict__ bfc,
                                               float* __restrict__ out)
{
    __shared__ float hs[H_SZ];
    const int b = blockIdx.x, o = threadIdx.x;
    for (int i = o; i < H_SZ; i += 128) hs[i] = hT[(size_t)b * H_SZ + i];
    __syncthreads();
    const float4* w4 = (const float4*)(Wfc + (size_t)o * H_SZ);
    const float4* h4 = (const float4*)hs;
    float acc = 0.f;
#pragma unroll 4
    for (int k = 0; k < H_SZ / 4; k++) {
        float4 w = w4[k], h = h4[k];
        acc += w.x * h.x + w.y * h.y + w.z * h.z + w.w * h.w;
    }
    out[(size_t)b * O_SZ + o] = acc + bfc[o];
}

// ---------------- launch ----------------

extern "C" void kernel_launch(void* const* d_in, const int* in_sizes, int n_in,
                              void* d_out, int out_size, void* d_ws, size_t ws_size,
                              hipStream_t stream) {
    const float* x     = (const float*)d_in[0];
    const float* W_ih0 = (const float*)d_in[1];
    const float* W_hh0 = (const float*)d_in[2];
    const float* b_ih0 = (const float*)d_in[3];
    const float* b_hh0 = (const float*)d_in[4];
    const float* h0_0  = (const float*)d_in[5];
    const float* W_ih1 = (const float*)d_in[6];
    const float* W_hh1 = (const float*)d_in[7];
    const float* b_ih1 = (const float*)d_in[8];
    const float* b_hh1 = (const float*)d_in[9];
    const float* h0_1  = (const float*)d_in[10];
    const float* W_fc  = (const float*)d_in[11];
    const float* b_fc  = (const float*)d_in[12];

    char* ws = (char*)d_ws;
    size_t off = 0;
    const size_t bufElems = (size_t)B_SZ * T_SZ * H_SZ;          // 67,108,864
    half_t* bufA  = (half_t*)(ws + off); off += bufElems * 2;    // xp0 -> res (in place)
    half_t* bufB  = (half_t*)(ws + off); off += bufElems * 2;    // xp1
    half_t* Wih0h = (half_t*)(ws + off); off += (size_t)H_SZ * F_SZ * 2;
    half_t* Wih1h = (half_t*)(ws + off); off += (size_t)H_SZ * H_SZ * 2;
    float*  hTbuf = (float*)(ws + off);  off += (size_t)B_SZ * H_SZ * 4;
    // exchange chunks: 2 layers x [64][2][4][128] half
    half_t* xch0  = (half_t*)(ws + off); off += (size_t)64 * 2 * 4 * 128 * 2;
    half_t* xch1  = (half_t*)(ws + off); off += (size_t)64 * 2 * 4 * 128 * 2;
    // flags: 2 layers x [64][4][16] uint
    const int FLAG_N = 64 * 4 * 16;
    unsigned int* flags0 = (unsigned int*)(ws + off); off += (size_t)FLAG_N * 4;
    unsigned int* flags1 = (unsigned int*)(ws + off); off += (size_t)FLAG_N * 4;

    const int M = B_SZ * T_SZ;   // 131072

    // prep
    zero_flags<<<(2 * FLAG_N + 255) / 256, 256, 0, stream>>>(flags0, 2 * FLAG_N);
    cvt_f32_f16<<<(H_SZ * F_SZ + 255) / 256, 256, 0, stream>>>(W_ih0, Wih0h, H_SZ * F_SZ);
    cvt_f32_f16<<<(H_SZ * H_SZ + 255) / 256, 256, 0, stream>>>(W_ih1, Wih1h, H_SZ * H_SZ);

    // xp0 = x @ W_ih0^T + b_ih0 + b_hh0
    gemm_xp<true, F_SZ><<<(M / 64) * 8, 256, 0, stream>>>(x, Wih0h, b_ih0, b_hh0, bufA);
    // layer-0 recurrence (res overwrites xp0 in place)
    rnn_rec4<<<256, 512, 0, stream>>>(bufA, 1, W_hh0, h0_0, nullptr, xch0, flags0);
    // xp1 = res @ W_ih1^T + b_ih1 + b_hh1
    gemm_xp<false, H_SZ><<<(M / 64) * 8, 256, 0, stream>>>(bufA, Wih1h, b_ih1, b_hh1, bufB);
    // layer-1 recurrence, keep only final hidden
    rnn_rec4<<<256, 512, 0, stream>>>(bufB, 0, W_hh1, h0_1, hTbuf, xch1, flags1);
    // head
    head_fc<<<B_SZ, 128, 0, stream>>>(hTbuf, W_fc, b_fc, (float*)d_out);
}

// Round 3
// 8065.260 us; speedup vs baseline: 4.3784x; 4.3784x over previous
//
#include <hip/hip_runtime.h>

typedef _Float16 half_t;
typedef _Float16 f16x2 __attribute__((ext_vector_type(2)));
typedef _Float16 f16x8 __attribute__((ext_vector_type(8)));
typedef float f32x4 __attribute__((ext_vector_type(4)));

#define B_SZ 64
#define T_SZ 2048
#define F_SZ 256
#define H_SZ 512
#define O_SZ 128
#define KREG 48   // half2-pairs per row kept in VGPRs (of 64); rest (16) in LDS

#if defined(__has_builtin)
#if __has_builtin(__builtin_amdgcn_fdot2)
#define HAS_FDOT2 1
#endif
#endif
#ifndef HAS_FDOT2
#define HAS_FDOT2 0
#endif

static __device__ __forceinline__ float fdot2(unsigned int w, unsigned int h, float acc) {
#if HAS_FDOT2
    return __builtin_amdgcn_fdot2(__builtin_bit_cast(f16x2, w), __builtin_bit_cast(f16x2, h), acc, false);
#else
    f16x2 wv = __builtin_bit_cast(f16x2, w);
    f16x2 hv = __builtin_bit_cast(f16x2, h);
    return acc + (float)wv[0] * (float)hv[0] + (float)wv[1] * (float)hv[1];
#endif
}

// ---------------- prep ----------------

__global__ void cvt_f32_f16(const float* __restrict__ src, half_t* __restrict__ dst, int n) {
    int i = blockIdx.x * 256 + threadIdx.x;
    if (i < n) dst[i] = (half_t)src[i];
}

// ---------------- input-projection GEMM (MFMA f16) ----------------
template<bool A_F32, int K>
__global__ __launch_bounds__(256) void gemm_xp(const void* __restrict__ Aptr,
                                               const half_t* __restrict__ Bw,
                                               const float* __restrict__ bias1,
                                               const float* __restrict__ bias2,
                                               half_t* __restrict__ Cout)
{
    const int nt   = blockIdx.x & 7;     // N/64 = 8
    const int mt   = blockIdx.x >> 3;
    const int wave = threadIdx.x >> 6;
    const int lane = threadIdx.x & 63;
    const int mrow = mt * 64 + wave * 16 + (lane & 15);
    const int koff = (lane >> 4) * 8;

    f32x4 acc[4];
#pragma unroll
    for (int i = 0; i < 4; i++) acc[i] = (f32x4){0.f, 0.f, 0.f, 0.f};

#pragma unroll 2
    for (int k0 = 0; k0 < K; k0 += 32) {
        f16x8 a;
        if (A_F32) {
            const float* ap = (const float*)Aptr + (size_t)mrow * K + (k0 + koff);
            float4 v0 = ((const float4*)ap)[0];
            float4 v1 = ((const float4*)ap)[1];
            a[0] = (half_t)v0.x; a[1] = (half_t)v0.y; a[2] = (half_t)v0.z; a[3] = (half_t)v0.w;
            a[4] = (half_t)v1.x; a[5] = (half_t)v1.y; a[6] = (half_t)v1.z; a[7] = (half_t)v1.w;
        } else {
            const half_t* ap = (const half_t*)Aptr + (size_t)mrow * K + (k0 + koff);
            a = *(const f16x8*)ap;
        }
#pragma unroll
        for (int cb = 0; cb < 4; cb++) {
            const int col = nt * 64 + cb * 16 + (lane & 15);
            f16x8 bfrag = *(const f16x8*)(Bw + (size_t)col * K + (k0 + koff));
            acc[cb] = __builtin_amdgcn_mfma_f32_16x16x32_f16(a, bfrag, acc[cb], 0, 0, 0);
        }
    }
    const int rbase = mt * 64 + wave * 16 + (lane >> 4) * 4;
#pragma unroll
    for (int cb = 0; cb < 4; cb++) {
        const int col = nt * 64 + cb * 16 + (lane & 15);
        const float bsum = bias1[col] + bias2[col];
#pragma unroll
        for (int r = 0; r < 4; r++) {
            Cout[(size_t)(rbase + r) * H_SZ + col] = (half_t)(acc[cb][r] + bsum);
        }
    }
}

// ---------------- recurrence: W_hh fully CU-resident (regs + LDS) ----------------
// One WG (512 threads) per batch row. Thread (o=tid&127, s=tid>>7) owns output
// rows j = o+128r (r=0..3) over k-slice [128s, 128s+128).
// Per row: 64 half2 of W; k2<KREG in VGPRs (4*KREG regs), k2>=KREG in LDS
// (4*(64-KREG) uint4-packed -> 16 uint4/thread, 128 KB total).
// Per step: dot (regs + LDS W, h broadcast from LDS) -> partials in LDS ->
// reduce + tanh -> h_sh update. 2 barriers/step, zero global W traffic.
__global__ __launch_bounds__(512, 2)
void rnn_recW(half_t* xpres,                   // [B,T,512] xp in (res out in place if store_res)
              const int store_res,
              const float* __restrict__ Whh,   // [512,512] f32
              const float* __restrict__ h0,    // [512]
              float* hT)                       // [B,512] or nullptr
{
    __shared__ __align__(16) half_t h_sh[H_SZ];        // 1 KB
    __shared__ float part[4 * H_SZ];                   // 8 KB
    __shared__ __align__(16) uint4 wlds[16 * 512];     // 128 KB

    const int tid = threadIdx.x;
    const int b   = blockIdx.x;
    const int o   = tid & 127;
    const int s   = tid >> 7;

    // ---- one-time init: W slice -> 192 VGPRs + 16 uint4 LDS ----
    unsigned int wreg[4 * KREG];
#pragma unroll
    for (int r = 0; r < 4; r++) {
        const float* wrow = Whh + (size_t)(o + 128 * r) * H_SZ + s * 128;
#pragma unroll
        for (int k2 = 0; k2 < KREG; k2++) {
            f16x2 p;
            p[0] = (half_t)wrow[2 * k2];
            p[1] = (half_t)wrow[2 * k2 + 1];
            wreg[k2 * 4 + r] = __builtin_bit_cast(unsigned int, p);
        }
#pragma unroll
        for (int c2 = 0; c2 < 4; c2++) {
            uint4 v;
            unsigned int q[4];
#pragma unroll
            for (int qq = 0; qq < 4; qq++) {
                int k2 = KREG + c2 * 4 + qq;
                f16x2 p;
                p[0] = (half_t)wrow[2 * k2];
                p[1] = (half_t)wrow[2 * k2 + 1];
                q[qq] = __builtin_bit_cast(unsigned int, p);
            }
            v.x = q[0]; v.y = q[1]; v.z = q[2]; v.w = q[3];
            wlds[(r * 4 + c2) * 512 + tid] = v;
        }
    }
    h_sh[tid] = (half_t)h0[tid];
    __syncthreads();

    const size_t base = (size_t)b * T_SZ * H_SZ;
    const uint4* hs4 = (const uint4*)h_sh + s * 16;   // wave-uniform (s uniform per wave)

    float xpv_next = (float)xpres[base + tid];        // prefetch t=0

#pragma unroll 1
    for (int t = 0; t < T_SZ; t++) {
        const float xpv = xpv_next;
        if (t + 1 < T_SZ)
            xpv_next = (float)xpres[base + (size_t)(t + 1) * H_SZ + tid];

        float acc0 = 0.f, acc1 = 0.f, acc2 = 0.f, acc3 = 0.f;
        // register-held W: k2 in [0, KREG)
#pragma unroll
        for (int c = 0; c < KREG / 4; c++) {
            uint4 h4 = hs4[c];
            acc0 = fdot2(wreg[(4 * c + 0) * 4 + 0], h4.x, acc0);
            acc1 = fdot2(wreg[(4 * c + 0) * 4 + 1], h4.x, acc1);
            acc2 = fdot2(wreg[(4 * c + 0) * 4 + 2], h4.x, acc2);
            acc3 = fdot2(wreg[(4 * c + 0) * 4 + 3], h4.x, acc3);
            acc0 = fdot2(wreg[(4 * c + 1) * 4 + 0], h4.y, acc0);
            acc1 = fdot2(wreg[(4 * c + 1) * 4 + 1], h4.y, acc1);
            acc2 = fdot2(wreg[(4 * c + 1) * 4 + 2], h4.y, acc2);
            acc3 = fdot2(wreg[(4 * c + 1) * 4 + 3], h4.y, acc3);
            acc0 = fdot2(wreg[(4 * c + 2) * 4 + 0], h4.z, acc0);
            acc1 = fdot2(wreg[(4 * c + 2) * 4 + 1], h4.z, acc1);
            acc2 = fdot2(wreg[(4 * c + 2) * 4 + 2], h4.z, acc2);
            acc3 = fdot2(wreg[(4 * c + 2) * 4 + 3], h4.z, acc3);
            acc0 = fdot2(wreg[(4 * c + 3) * 4 + 0], h4.w, acc0);
            acc1 = fdot2(wreg[(4 * c + 3) * 4 + 1], h4.w, acc1);
            acc2 = fdot2(wreg[(4 * c + 3) * 4 + 2], h4.w, acc2);
            acc3 = fdot2(wreg[(4 * c + 3) * 4 + 3], h4.w, acc3);
        }
        // LDS-held W: k2 in [KREG, 64)
#pragma unroll
        for (int c2 = 0; c2 < 4; c2++) {
            uint4 h4 = hs4[KREG / 4 + c2];
            uint4 w0 = wlds[(0 * 4 + c2) * 512 + tid];
            uint4 w1 = wlds[(1 * 4 + c2) * 512 + tid];
            uint4 w2 = wlds[(2 * 4 + c2) * 512 + tid];
            uint4 w3 = wlds[(3 * 4 + c2) * 512 + tid];
            acc0 = fdot2(w0.x, h4.x, acc0); acc0 = fdot2(w0.y, h4.y, acc0);
            acc0 = fdot2(w0.z, h4.z, acc0); acc0 = fdot2(w0.w, h4.w, acc0);
            acc1 = fdot2(w1.x, h4.x, acc1); acc1 = fdot2(w1.y, h4.y, acc1);
            acc1 = fdot2(w1.z, h4.z, acc1); acc1 = fdot2(w1.w, h4.w, acc1);
            acc2 = fdot2(w2.x, h4.x, acc2); acc2 = fdot2(w2.y, h4.y, acc2);
            acc2 = fdot2(w2.z, h4.z, acc2); acc2 = fdot2(w2.w, h4.w, acc2);
            acc3 = fdot2(w3.x, h4.x, acc3); acc3 = fdot2(w3.y, h4.y, acc3);
            acc3 = fdot2(w3.z, h4.z, acc3); acc3 = fdot2(w3.w, h4.w, acc3);
        }

        part[s * H_SZ + o]       = acc0;
        part[s * H_SZ + o + 128] = acc1;
        part[s * H_SZ + o + 256] = acc2;
        part[s * H_SZ + o + 384] = acc3;
        __syncthreads();   // partials visible; all h_sh reads of this step done

        float y = part[tid] + part[H_SZ + tid] + part[2 * H_SZ + tid] + part[3 * H_SZ + tid] + xpv;
        // tanh(y) = 1 - 2/(exp(2y)+1)  (v_exp + v_rcp; exact at saturation)
        float e  = __expf(2.0f * y);
        float hn = 1.0f - 2.0f / (e + 1.0f);
        h_sh[tid] = (half_t)hn;
        if (store_res) xpres[base + (size_t)t * H_SZ + tid] = (half_t)hn;
        if (hT != nullptr && t == T_SZ - 1) hT[(size_t)b * H_SZ + tid] = hn;
        __syncthreads();   // h_sh update visible for next step
    }
}

// ---------------- head ----------------
__global__ __launch_bounds__(128) void head_fc(const float* __restrict__ hT,
                                               const float* __restrict__ Wfc,
                                               const float* __restrict__ bfc,
                                               float* __restrict__ out)
{
    __shared__ float hs[H_SZ];
    const int b = blockIdx.x, o = threadIdx.x;
    for (int i = o; i < H_SZ; i += 128) hs[i] = hT[(size_t)b * H_SZ + i];
    __syncthreads();
    const float4* w4 = (const float4*)(Wfc + (size_t)o * H_SZ);
    const float4* h4 = (const float4*)hs;
    float acc = 0.f;
#pragma unroll 4
    for (int k = 0; k < H_SZ / 4; k++) {
        float4 w = w4[k], h = h4[k];
        acc += w.x * h.x + w.y * h.y + w.z * h.z + w.w * h.w;
    }
    out[(size_t)b * O_SZ + o] = acc + bfc[o];
}

// ---------------- launch ----------------

extern "C" void kernel_launch(void* const* d_in, const int* in_sizes, int n_in,
                              void* d_out, int out_size, void* d_ws, size_t ws_size,
                              hipStream_t stream) {
    const float* x     = (const float*)d_in[0];
    const float* W_ih0 = (const float*)d_in[1];
    const float* W_hh0 = (const float*)d_in[2];
    const float* b_ih0 = (const float*)d_in[3];
    const float* b_hh0 = (const float*)d_in[4];
    const float* h0_0  = (const float*)d_in[5];
    const float* W_ih1 = (const float*)d_in[6];
    const float* W_hh1 = (const float*)d_in[7];
    const float* b_ih1 = (const float*)d_in[8];
    const float* b_hh1 = (const float*)d_in[9];
    const float* h0_1  = (const float*)d_in[10];
    const float* W_fc  = (const float*)d_in[11];
    const float* b_fc  = (const float*)d_in[12];

    char* ws = (char*)d_ws;
    size_t off = 0;
    const size_t bufElems = (size_t)B_SZ * T_SZ * H_SZ;          // 67,108,864
    half_t* bufA  = (half_t*)(ws + off); off += bufElems * 2;    // xp0 -> res (in place)
    half_t* bufB  = (half_t*)(ws + off); off += bufElems * 2;    // xp1
    half_t* Wih0h = (half_t*)(ws + off); off += (size_t)H_SZ * F_SZ * 2;
    half_t* Wih1h = (half_t*)(ws + off); off += (size_t)H_SZ * H_SZ * 2;
    float*  hTbuf = (float*)(ws + off);  off += (size_t)B_SZ * H_SZ * 4;

    const int M = B_SZ * T_SZ;   // 131072

    cvt_f32_f16<<<(H_SZ * F_SZ + 255) / 256, 256, 0, stream>>>(W_ih0, Wih0h, H_SZ * F_SZ);
    cvt_f32_f16<<<(H_SZ * H_SZ + 255) / 256, 256, 0, stream>>>(W_ih1, Wih1h, H_SZ * H_SZ);

    // xp0 = x @ W_ih0^T + b_ih0 + b_hh0
    gemm_xp<true, F_SZ><<<(M / 64) * 8, 256, 0, stream>>>(x, Wih0h, b_ih0, b_hh0, bufA);
    // layer-0 recurrence (res overwrites xp0 in place)
    rnn_recW<<<B_SZ, 512, 0, stream>>>(bufA, 1, W_hh0, h0_0, nullptr);
    // xp1 = res @ W_ih1^T + b_ih1 + b_hh1
    gemm_xp<false, H_SZ><<<(M / 64) * 8, 256, 0, stream>>>(bufA, Wih1h, b_ih1, b_hh1, bufB);
    // layer-1 recurrence, keep only final hidden
    rnn_recW<<<B_SZ, 512, 0, stream>>>(bufB, 0, W_hh1, h0_1, hTbuf);
    // head
    head_fc<<<B_SZ, 128, 0, stream>>>(hTbuf, W_fc, b_fc, (float*)d_out);
}